// Round 1
// baseline (1205.005 us; speedup 1.0000x reference)
//
#include <hip/hip_runtime.h>

// Problem constants: B=1, T=2048, D=2048, H=16, HD=128
#define TT 2048
#define DD 2048
#define NH 16
#define HDIM 128

// ---------------------------------------------------------------------------
// SGEMM: C[2048x2048] = A[2048x2048] @ B[2048x2048], fp32 vector ALU.
// 128x128 block tile, BK=8, 256 threads, 8x8 micro-tile per thread,
// register-prefetch of next K-tile to hide global latency.
// ---------------------------------------------------------------------------
__global__ __launch_bounds__(256) void sgemm_kernel(const float* __restrict__ A,
                                                    const float* __restrict__ B,
                                                    float* __restrict__ C) {
    constexpr int BM = 128, BN = 128, BK = 8;
    __shared__ float As[BK][BM];   // stored k-major (transposed) for b128 reads
    __shared__ float Bs[BK][BN];

    const int tid = threadIdx.x;
    const int tx = tid & 15;       // 0..15 -> col group
    const int ty = tid >> 4;       // 0..15 -> row group
    const int row0 = blockIdx.y * BM;
    const int col0 = blockIdx.x * BN;

    // A tile: 128 rows x 8 k -> one float4 per thread
    const int a_r = tid >> 1;            // 0..127
    const int a_k = (tid & 1) * 4;       // 0 or 4
    // B tile: 8 k x 128 cols -> one float4 per thread (coalesced)
    const int b_k = tid >> 5;            // 0..7
    const int b_c = (tid & 31) * 4;      // 0..124

    float acc[8][8];
#pragma unroll
    for (int i = 0; i < 8; ++i)
#pragma unroll
        for (int j = 0; j < 8; ++j) acc[i][j] = 0.f;

    // prefetch first tile into registers
    float4 av = *(const float4*)(A + (size_t)(row0 + a_r) * DD + a_k);
    float4 bv = *(const float4*)(B + (size_t)b_k * DD + col0 + b_c);

    for (int k0 = 0; k0 < DD; k0 += BK) {
        // commit prefetched tile to LDS
        As[a_k + 0][a_r] = av.x;
        As[a_k + 1][a_r] = av.y;
        As[a_k + 2][a_r] = av.z;
        As[a_k + 3][a_r] = av.w;
        *(float4*)&Bs[b_k][b_c] = bv;
        __syncthreads();

        // prefetch next tile (registers) while computing on LDS
        const int kn = k0 + BK;
        if (kn < DD) {
            av = *(const float4*)(A + (size_t)(row0 + a_r) * DD + kn + a_k);
            bv = *(const float4*)(B + (size_t)(kn + b_k) * DD + col0 + b_c);
        }

#pragma unroll
        for (int kk = 0; kk < BK; ++kk) {
            float4 a0 = *(float4*)&As[kk][ty * 8];
            float4 a1 = *(float4*)&As[kk][ty * 8 + 4];
            float4 b0 = *(float4*)&Bs[kk][tx * 8];
            float4 b1 = *(float4*)&Bs[kk][tx * 8 + 4];
            float ar[8] = {a0.x, a0.y, a0.z, a0.w, a1.x, a1.y, a1.z, a1.w};
            float br[8] = {b0.x, b0.y, b0.z, b0.w, b1.x, b1.y, b1.z, b1.w};
#pragma unroll
            for (int i = 0; i < 8; ++i)
#pragma unroll
                for (int j = 0; j < 8; ++j)
                    acc[i][j] = fmaf(ar[i], br[j], acc[i][j]);
        }
        __syncthreads();
    }

#pragma unroll
    for (int i = 0; i < 8; ++i) {
        float* crow = C + (size_t)(row0 + ty * 8 + i) * DD + col0 + tx * 8;
        float4 o0 = {acc[i][0], acc[i][1], acc[i][2], acc[i][3]};
        float4 o1 = {acc[i][4], acc[i][5], acc[i][6], acc[i][7]};
        *(float4*)(crow) = o0;
        *(float4*)(crow + 4) = o1;
    }
}

// ---------------------------------------------------------------------------
// RoPE applied in-place to Q and K. One thread per (t, h, i<64) pair handles
// both halves of the rotation -> no races, coalesced within rows.
// out[i]    = u[i]*cos[i]    - u[i+64]*sin[i]      (i <  64)
// out[i+64] = u[i+64]*cos[i+64] + u[i]*sin[i+64]
// ---------------------------------------------------------------------------
__global__ __launch_bounds__(256) void rope_kernel(float* __restrict__ Q,
                                                   float* __restrict__ K,
                                                   const float* __restrict__ sn,
                                                   const float* __restrict__ cs) {
    const int idx = blockIdx.x * blockDim.x + threadIdx.x;  // T*NH*64 total
    const int i = idx & 63;
    const int h = (idx >> 6) & (NH - 1);
    const int t = idx >> 10;            // / (64*16)
    const float s1 = sn[t * HDIM + i];
    const float c1 = cs[t * HDIM + i];
    const float s2 = sn[t * HDIM + i + 64];
    const float c2 = cs[t * HDIM + i + 64];
    const size_t base = (size_t)t * DD + h * HDIM + i;
    const float q1 = Q[base], q2 = Q[base + 64];
    Q[base]      = fmaf(q1, c1, -q2 * s1);
    Q[base + 64] = fmaf(q2, c2,  q1 * s2);
    const float k1 = K[base], k2 = K[base + 64];
    K[base]      = fmaf(k1, c1, -k2 * s1);
    K[base + 64] = fmaf(k2, c2,  k1 * s2);
}

// ---------------------------------------------------------------------------
// Flash-style attention, fp32, one workgroup per (q-block of 64, head).
// Online softmax; doc mask exploited: sorted doc_ids -> per-block binary
// search for the earliest same-doc position, skip tiles outside
// [doc_start(q0), q_last]. Masked scores use -1e30 (finite): fully-masked
// early tiles accumulate garbage that is exactly annihilated once a real
// tile raises the running max (alpha = exp(-1e30 - m_real) == 0).
// ---------------------------------------------------------------------------
__global__ __launch_bounds__(256) void attn_kernel(const float* __restrict__ Q,
                                                   const float* __restrict__ K,
                                                   const float* __restrict__ V,
                                                   const int* __restrict__ doc_ids,
                                                   float* __restrict__ Aout) {
    constexpr int BQ = 64, BS = 32;
    __shared__ float Qs[BQ][HDIM + 4];     // +4 pad: row start bank = 4*r%32
    __shared__ float KVs[BS][HDIM + 4];    // K tile, then reused for V tile
    __shared__ float Ps[BQ][BS + 1];
    __shared__ int qdoc[BQ];
    __shared__ int sdoc[BS];

    const int tid = threadIdx.x;
    const int tx = tid & 15;
    const int ty = tid >> 4;
    const int h = blockIdx.y;
    const int q0 = blockIdx.x * BQ;

    // load Q tile (64 x 128 = 2048 float4, 8 per thread)
#pragma unroll
    for (int it = 0; it < 8; ++it) {
        const int f4 = tid + it * 256;
        const int r = f4 >> 5;
        const int c4 = (f4 & 31) * 4;
        *(float4*)&Qs[r][c4] = *(const float4*)(Q + (size_t)(q0 + r) * DD + h * HDIM + c4);
    }
    if (tid < BQ) qdoc[tid] = doc_ids[q0 + tid];

    float m_i[4], l_i[4], O[4][8];
#pragma unroll
    for (int i = 0; i < 4; ++i) {
        m_i[i] = -1e30f;
        l_i[i] = 0.f;
#pragma unroll
        for (int c = 0; c < 8; ++c) O[i][c] = 0.f;
    }

    // binary search: first index with doc_ids[idx] == doc_ids[q0]
    const int d0 = doc_ids[q0];
    int lo = 0, hi = q0;
    while (lo < hi) {
        const int mid = (lo + hi) >> 1;
        if (doc_ids[mid] < d0) lo = mid + 1; else hi = mid;
    }
    const int s_begin = lo & ~(BS - 1);
    const int s_end = q0 + BQ;   // exclusive (causal upper bound for this block)

    __syncthreads();

    for (int s0 = s_begin; s0 < s_end; s0 += BS) {
        // ---- load K tile ----
#pragma unroll
        for (int it = 0; it < 4; ++it) {
            const int f4 = tid + it * 256;
            const int r = f4 >> 5;
            const int c4 = (f4 & 31) * 4;
            *(float4*)&KVs[r][c4] = *(const float4*)(K + (size_t)(s0 + r) * DD + h * HDIM + c4);
        }
        if (tid < BS) sdoc[tid] = doc_ids[s0 + tid];
        __syncthreads();

        // ---- scores: rows ty*4+i, cols {tx, tx+16} ----
        float s_acc[4][2];
#pragma unroll
        for (int i = 0; i < 4; ++i) { s_acc[i][0] = 0.f; s_acc[i][1] = 0.f; }
#pragma unroll 8
        for (int d = 0; d < HDIM; d += 4) {
            const float4 k0 = *(float4*)&KVs[tx][d];
            const float4 k1 = *(float4*)&KVs[tx + 16][d];
#pragma unroll
            for (int i = 0; i < 4; ++i) {
                const float4 q = *(float4*)&Qs[ty * 4 + i][d];
                s_acc[i][0] = fmaf(q.x, k0.x, fmaf(q.y, k0.y, fmaf(q.z, k0.z, fmaf(q.w, k0.w, s_acc[i][0]))));
                s_acc[i][1] = fmaf(q.x, k1.x, fmaf(q.y, k1.y, fmaf(q.z, k1.z, fmaf(q.w, k1.w, s_acc[i][1]))));
            }
        }

        // ---- mask + online softmax update ----
        const float scale = 0.08838834764831845f;  // 1/sqrt(128)
        float alpha_r[4];
#pragma unroll
        for (int i = 0; i < 4; ++i) {
            const int r = ty * 4 + i;
            const int qg = q0 + r;
            const int dq = qdoc[r];
            const bool v0 = (s0 + tx <= qg) && (sdoc[tx] == dq);
            const bool v1 = (s0 + tx + 16 <= qg) && (sdoc[tx + 16] == dq);
            s_acc[i][0] = v0 ? s_acc[i][0] * scale : -1e30f;
            s_acc[i][1] = v1 ? s_acc[i][1] * scale : -1e30f;
            float m = fmaxf(s_acc[i][0], s_acc[i][1]);
            m = fmaxf(m, __shfl_xor(m, 1));
            m = fmaxf(m, __shfl_xor(m, 2));
            m = fmaxf(m, __shfl_xor(m, 4));
            m = fmaxf(m, __shfl_xor(m, 8));
            const float mn = fmaxf(m_i[i], m);
            const float p0 = __expf(s_acc[i][0] - mn);
            const float p1 = __expf(s_acc[i][1] - mn);
            float ts = p0 + p1;
            ts += __shfl_xor(ts, 1);
            ts += __shfl_xor(ts, 2);
            ts += __shfl_xor(ts, 4);
            ts += __shfl_xor(ts, 8);
            const float alpha = __expf(m_i[i] - mn);
            l_i[i] = l_i[i] * alpha + ts;
            m_i[i] = mn;
            alpha_r[i] = alpha;
            Ps[r][tx] = p0;
            Ps[r][tx + 16] = p1;
        }
        __syncthreads();   // K reads + Ps writes complete

        // ---- load V tile over K tile ----
#pragma unroll
        for (int it = 0; it < 4; ++it) {
            const int f4 = tid + it * 256;
            const int r = f4 >> 5;
            const int c4 = (f4 & 31) * 4;
            *(float4*)&KVs[r][c4] = *(const float4*)(V + (size_t)(s0 + r) * DD + h * HDIM + c4);
        }
        __syncthreads();

        // ---- O = O*alpha + P @ V  (rows ty*4+i, cols tx*8..tx*8+7) ----
#pragma unroll
        for (int i = 0; i < 4; ++i)
#pragma unroll
            for (int c = 0; c < 8; ++c) O[i][c] *= alpha_r[i];

#pragma unroll 4
        for (int s = 0; s < BS; ++s) {
            const float4 v0 = *(float4*)&KVs[s][tx * 8];
            const float4 v1 = *(float4*)&KVs[s][tx * 8 + 4];
#pragma unroll
            for (int i = 0; i < 4; ++i) {
                const float p = Ps[ty * 4 + i][s];
                O[i][0] = fmaf(p, v0.x, O[i][0]);
                O[i][1] = fmaf(p, v0.y, O[i][1]);
                O[i][2] = fmaf(p, v0.z, O[i][2]);
                O[i][3] = fmaf(p, v0.w, O[i][3]);
                O[i][4] = fmaf(p, v1.x, O[i][4]);
                O[i][5] = fmaf(p, v1.y, O[i][5]);
                O[i][6] = fmaf(p, v1.z, O[i][6]);
                O[i][7] = fmaf(p, v1.w, O[i][7]);
            }
        }
        __syncthreads();   // done with KVs/Ps before next tile overwrites
    }

    // ---- normalize + store ----
#pragma unroll
    for (int i = 0; i < 4; ++i) {
        const int r = ty * 4 + i;
        const float inv = 1.f / l_i[i];
        float* dst = Aout + (size_t)(q0 + r) * DD + h * HDIM + tx * 8;
        float4 o0 = {O[i][0] * inv, O[i][1] * inv, O[i][2] * inv, O[i][3] * inv};
        float4 o1 = {O[i][4] * inv, O[i][5] * inv, O[i][6] * inv, O[i][7] * inv};
        *(float4*)dst = o0;
        *(float4*)(dst + 4) = o1;
    }
}

// ---------------------------------------------------------------------------
// Launch: 3 projection GEMMs -> RoPE(Q,K) -> flash attention -> output GEMM.
// Workspace: Q, K, V, attn-out = 4 x 16 MB = 64 MB of d_ws.
// ---------------------------------------------------------------------------
extern "C" void kernel_launch(void* const* d_in, const int* in_sizes, int n_in,
                              void* d_out, int out_size, void* d_ws, size_t ws_size,
                              hipStream_t stream) {
    const float* x  = (const float*)d_in[0];
    const float* Wq = (const float*)d_in[1];
    const float* Wk = (const float*)d_in[2];
    const float* Wv = (const float*)d_in[3];
    const float* Wo = (const float*)d_in[4];
    const float* sn = (const float*)d_in[5];
    const float* cs = (const float*)d_in[6];
    const int* doc  = (const int*)d_in[7];
    float* out = (float*)d_out;

    float* Q  = (float*)d_ws;
    float* Kb = Q  + (size_t)TT * DD;
    float* Vb = Kb + (size_t)TT * DD;
    float* Ab = Vb + (size_t)TT * DD;

    const dim3 gg(DD / 128, TT / 128);   // 16 x 16
    const dim3 bb(256);

    sgemm_kernel<<<gg, bb, 0, stream>>>(x, Wq, Q);
    sgemm_kernel<<<gg, bb, 0, stream>>>(x, Wk, Kb);
    sgemm_kernel<<<gg, bb, 0, stream>>>(x, Wv, Vb);
    rope_kernel<<<dim3((TT * NH * 64) / 256), bb, 0, stream>>>(Q, Kb, sn, cs);
    attn_kernel<<<dim3(TT / 64, NH), bb, 0, stream>>>(Q, Kb, Vb, doc, Ab);
    sgemm_kernel<<<gg, bb, 0, stream>>>(Ab, Wo, out);
}

// Round 3
// 408.649 us; speedup vs baseline: 2.9487x; 2.9487x over previous
//
#include <hip/hip_runtime.h>

// Problem constants: B=1, T=2048, D=2048, H=16, HD=128
#define TT 2048
#define DD 2048
#define NH 16
#define HDIM 128

typedef _Float16 half8 __attribute__((ext_vector_type(8)));
typedef _Float16 half4 __attribute__((ext_vector_type(4)));
typedef float floatx4 __attribute__((ext_vector_type(4)));

// ---------------------------------------------------------------------------
// fp32 -> f16 elementwise convert (4 elems/thread, float4 in, half4 out)
// ---------------------------------------------------------------------------
__global__ __launch_bounds__(256) void conv_f16_kernel(const float* __restrict__ in,
                                                       _Float16* __restrict__ out) {
    const int i = (blockIdx.x * 256 + threadIdx.x) * 4;
    const float4 v = *(const float4*)(in + i);
    half4 o;
    o[0] = (_Float16)v.x; o[1] = (_Float16)v.y;
    o[2] = (_Float16)v.z; o[3] = (_Float16)v.w;
    *(half4*)(out + i) = o;
}

// ---------------------------------------------------------------------------
// fp32 W[K][N] -> f16 Wt[N][K] transpose+convert, 32x32 LDS tile.
// blockIdx.z selects which of the 4 weight matrices.
// ---------------------------------------------------------------------------
__global__ __launch_bounds__(256) void tconv_kernel(const float* __restrict__ W0,
                                                    const float* __restrict__ W1,
                                                    const float* __restrict__ W2,
                                                    const float* __restrict__ W3,
                                                    _Float16* __restrict__ O0,
                                                    _Float16* __restrict__ O1,
                                                    _Float16* __restrict__ O2,
                                                    _Float16* __restrict__ O3) {
    const float* W = blockIdx.z == 0 ? W0 : (blockIdx.z == 1 ? W1 : (blockIdx.z == 2 ? W2 : W3));
    _Float16* O = blockIdx.z == 0 ? O0 : (blockIdx.z == 1 ? O1 : (blockIdx.z == 2 ? O2 : O3));
    __shared__ float T[32][33];
    const int tx = threadIdx.x & 7;    // *4 cols
    const int ty = threadIdx.x >> 3;   // 0..31
    const int k0 = blockIdx.y * 32;
    const int n0 = blockIdx.x * 32;
    const float4 v = *(const float4*)(W + (size_t)(k0 + ty) * DD + n0 + tx * 4);
    T[ty][tx * 4 + 0] = v.x;
    T[ty][tx * 4 + 1] = v.y;
    T[ty][tx * 4 + 2] = v.z;
    T[ty][tx * 4 + 3] = v.w;
    __syncthreads();
    half4 o;
    o[0] = (_Float16)T[tx * 4 + 0][ty];
    o[1] = (_Float16)T[tx * 4 + 1][ty];
    o[2] = (_Float16)T[tx * 4 + 2][ty];
    o[3] = (_Float16)T[tx * 4 + 3][ty];
    *(half4*)(O + (size_t)(n0 + ty) * DD + k0 + tx * 4) = o;
}

// ---------------------------------------------------------------------------
// MFMA f16 GEMM body: C[2048x2048] fp32 = A[M][K]f16 @ Bt[N][K]f16^T.
// 128x128 block tile, BK=32, 256 threads = 4 waves, each wave a 64x64
// sub-tile = 4x4 fragments of 16x16x32. global_load_lds width-16 staging
// with a 16B-block swizzle so ds_read_b128 fragment reads are conflict-free:
// LDS(r, blk) holds global k-block (blk + (r>>1)) & 3.
// ---------------------------------------------------------------------------
__device__ __forceinline__ void hgemm_body(const _Float16* __restrict__ A,
                                           const _Float16* __restrict__ Bt,
                                           float* __restrict__ C,
                                           const int row0, const int col0) {
    __shared__ __align__(16) _Float16 Al[128 * 32];
    __shared__ __align__(16) _Float16 Bl[128 * 32];

    const int tid = threadIdx.x;
    const int lane = tid & 63;
    const int w = tid >> 6;
    const int quad = lane >> 4;
    const int lr = lane & 15;
    const int wr = (w >> 1) * 64;
    const int wc = (w & 1) * 64;

    floatx4 acc[4][4];
#pragma unroll
    for (int i = 0; i < 4; ++i)
#pragma unroll
        for (int j = 0; j < 4; ++j)
            acc[i][j] = (floatx4){0.f, 0.f, 0.f, 0.f};

    // staging geometry: chunk = 16 rows x 32 k (1 KB); lane l -> LDS chunkbase + l*16B
    const int subrow = lane >> 2;       // 0..15
    const int lblk = lane & 3;          // 16B block within row

    for (int k0 = 0; k0 < DD; k0 += 32) {
#pragma unroll
        for (int i = 0; i < 2; ++i) {
            const int ch = w * 2 + i;
            const int r = ch * 16 + subrow;                 // tile row 0..127
            const int gb = (lblk + (r >> 1)) & 3;           // swizzled k-block
            const _Float16* ga = A + (size_t)(row0 + r) * DD + k0 + gb * 8;
            __builtin_amdgcn_global_load_lds(
                (const __attribute__((address_space(1))) void*)ga,
                (__attribute__((address_space(3))) void*)(Al + ch * 512), 16, 0, 0);
            const _Float16* gbp = Bt + (size_t)(col0 + r) * DD + k0 + gb * 8;
            __builtin_amdgcn_global_load_lds(
                (const __attribute__((address_space(1))) void*)gbp,
                (__attribute__((address_space(3))) void*)(Bl + ch * 512), 16, 0, 0);
        }
        __syncthreads();

        half8 af[4], bf[4];
#pragma unroll
        for (int i = 0; i < 4; ++i) {
            const int r = wr + i * 16 + lr;
            const int lb = (quad - (r >> 1)) & 3;
            af[i] = *(const half8*)&Al[r * 32 + lb * 8];
        }
#pragma unroll
        for (int j = 0; j < 4; ++j) {
            const int r = wc + j * 16 + lr;
            const int lb = (quad - (r >> 1)) & 3;
            bf[j] = *(const half8*)&Bl[r * 32 + lb * 8];
        }
#pragma unroll
        for (int i = 0; i < 4; ++i)
#pragma unroll
            for (int j = 0; j < 4; ++j)
                acc[i][j] = __builtin_amdgcn_mfma_f32_16x16x32_f16(af[i], bf[j], acc[i][j], 0, 0, 0);
        __syncthreads();
    }

    // epilogue: C/D layout col = lane&15, row = quad*4 + reg
#pragma unroll
    for (int i = 0; i < 4; ++i)
#pragma unroll
        for (int j = 0; j < 4; ++j) {
            const int col = col0 + wc + j * 16 + lr;
#pragma unroll
            for (int r = 0; r < 4; ++r) {
                const int row = row0 + wr + i * 16 + quad * 4 + r;
                C[(size_t)row * DD + col] = acc[i][j][r];
            }
        }
}

// QKV fused: blockIdx.z selects (W, C) pair -> 768 blocks = 3 blocks/CU.
__global__ __launch_bounds__(256) void qkv_gemm_kernel(const _Float16* __restrict__ xh,
                                                       const _Float16* __restrict__ Wqt,
                                                       const _Float16* __restrict__ Wkt,
                                                       const _Float16* __restrict__ Wvt,
                                                       float* __restrict__ Q,
                                                       float* __restrict__ K,
                                                       float* __restrict__ V) {
    const _Float16* Bt = blockIdx.z == 0 ? Wqt : (blockIdx.z == 1 ? Wkt : Wvt);
    float* C = blockIdx.z == 0 ? Q : (blockIdx.z == 1 ? K : V);
    hgemm_body(xh, Bt, C, blockIdx.y * 128, blockIdx.x * 128);
}

__global__ __launch_bounds__(256) void ogemm_kernel(const _Float16* __restrict__ Ah,
                                                    const _Float16* __restrict__ Wot,
                                                    float* __restrict__ C) {
    hgemm_body(Ah, Wot, C, blockIdx.y * 128, blockIdx.x * 128);
}

// ---------------------------------------------------------------------------
// RoPE applied in-place to Q and K (fp32).
// ---------------------------------------------------------------------------
__global__ __launch_bounds__(256) void rope_kernel(float* __restrict__ Q,
                                                   float* __restrict__ K,
                                                   const float* __restrict__ sn,
                                                   const float* __restrict__ cs) {
    const int idx = blockIdx.x * blockDim.x + threadIdx.x;  // T*NH*64 total
    const int i = idx & 63;
    const int h = (idx >> 6) & (NH - 1);
    const int t = idx >> 10;
    const float s1 = sn[t * HDIM + i];
    const float c1 = cs[t * HDIM + i];
    const float s2 = sn[t * HDIM + i + 64];
    const float c2 = cs[t * HDIM + i + 64];
    const size_t base = (size_t)t * DD + h * HDIM + i;
    const float q1 = Q[base], q2 = Q[base + 64];
    Q[base]      = fmaf(q1, c1, -q2 * s1);
    Q[base + 64] = fmaf(q2, c2,  q1 * s2);
    const float k1 = K[base], k2 = K[base + 64];
    K[base]      = fmaf(k1, c1, -k2 * s1);
    K[base + 64] = fmaf(k2, c2,  k1 * s2);
}

// ---------------------------------------------------------------------------
// Flash-style attention, fp32 compute, f16 output (feeds ogemm directly).
// Sorted doc_ids -> binary search for first same-doc position, skip tiles.
// ---------------------------------------------------------------------------
__global__ __launch_bounds__(256) void attn_kernel(const float* __restrict__ Q,
                                                   const float* __restrict__ K,
                                                   const float* __restrict__ V,
                                                   const int* __restrict__ doc_ids,
                                                   _Float16* __restrict__ Aout) {
    constexpr int BQ = 64, BS = 32;
    __shared__ float Qs[BQ][HDIM + 4];
    __shared__ float KVs[BS][HDIM + 4];
    __shared__ float Ps[BQ][BS + 1];
    __shared__ int qdoc[BQ];
    __shared__ int sdoc[BS];

    const int tid = threadIdx.x;
    const int tx = tid & 15;
    const int ty = tid >> 4;
    const int h = blockIdx.y;
    const int q0 = blockIdx.x * BQ;

#pragma unroll
    for (int it = 0; it < 8; ++it) {
        const int f4 = tid + it * 256;
        const int r = f4 >> 5;
        const int c4 = (f4 & 31) * 4;
        *(float4*)&Qs[r][c4] = *(const float4*)(Q + (size_t)(q0 + r) * DD + h * HDIM + c4);
    }
    if (tid < BQ) qdoc[tid] = doc_ids[q0 + tid];

    float m_i[4], l_i[4], O[4][8];
#pragma unroll
    for (int i = 0; i < 4; ++i) {
        m_i[i] = -1e30f;
        l_i[i] = 0.f;
#pragma unroll
        for (int c = 0; c < 8; ++c) O[i][c] = 0.f;
    }

    const int d0 = doc_ids[q0];
    int lo = 0, hi = q0;
    while (lo < hi) {
        const int mid = (lo + hi) >> 1;
        if (doc_ids[mid] < d0) lo = mid + 1; else hi = mid;
    }
    const int s_begin = lo & ~(BS - 1);
    const int s_end = q0 + BQ;

    __syncthreads();

    for (int s0 = s_begin; s0 < s_end; s0 += BS) {
#pragma unroll
        for (int it = 0; it < 4; ++it) {
            const int f4 = tid + it * 256;
            const int r = f4 >> 5;
            const int c4 = (f4 & 31) * 4;
            *(float4*)&KVs[r][c4] = *(const float4*)(K + (size_t)(s0 + r) * DD + h * HDIM + c4);
        }
        if (tid < BS) sdoc[tid] = doc_ids[s0 + tid];
        __syncthreads();

        float s_acc[4][2];
#pragma unroll
        for (int i = 0; i < 4; ++i) { s_acc[i][0] = 0.f; s_acc[i][1] = 0.f; }
#pragma unroll 8
        for (int d = 0; d < HDIM; d += 4) {
            const float4 k0 = *(float4*)&KVs[tx][d];
            const float4 k1 = *(float4*)&KVs[tx + 16][d];
#pragma unroll
            for (int i = 0; i < 4; ++i) {
                const float4 q = *(float4*)&Qs[ty * 4 + i][d];
                s_acc[i][0] = fmaf(q.x, k0.x, fmaf(q.y, k0.y, fmaf(q.z, k0.z, fmaf(q.w, k0.w, s_acc[i][0]))));
                s_acc[i][1] = fmaf(q.x, k1.x, fmaf(q.y, k1.y, fmaf(q.z, k1.z, fmaf(q.w, k1.w, s_acc[i][1]))));
            }
        }

        const float scale = 0.08838834764831845f;
        float alpha_r[4];
#pragma unroll
        for (int i = 0; i < 4; ++i) {
            const int r = ty * 4 + i;
            const int qg = q0 + r;
            const int dq = qdoc[r];
            const bool v0 = (s0 + tx <= qg) && (sdoc[tx] == dq);
            const bool v1 = (s0 + tx + 16 <= qg) && (sdoc[tx + 16] == dq);
            s_acc[i][0] = v0 ? s_acc[i][0] * scale : -1e30f;
            s_acc[i][1] = v1 ? s_acc[i][1] * scale : -1e30f;
            float m = fmaxf(s_acc[i][0], s_acc[i][1]);
            m = fmaxf(m, __shfl_xor(m, 1));
            m = fmaxf(m, __shfl_xor(m, 2));
            m = fmaxf(m, __shfl_xor(m, 4));
            m = fmaxf(m, __shfl_xor(m, 8));
            const float mn = fmaxf(m_i[i], m);
            const float p0 = __expf(s_acc[i][0] - mn);
            const float p1 = __expf(s_acc[i][1] - mn);
            float ts = p0 + p1;
            ts += __shfl_xor(ts, 1);
            ts += __shfl_xor(ts, 2);
            ts += __shfl_xor(ts, 4);
            ts += __shfl_xor(ts, 8);
            const float alpha = __expf(m_i[i] - mn);
            l_i[i] = l_i[i] * alpha + ts;
            m_i[i] = mn;
            alpha_r[i] = alpha;
            Ps[r][tx] = p0;
            Ps[r][tx + 16] = p1;
        }
        __syncthreads();

#pragma unroll
        for (int it = 0; it < 4; ++it) {
            const int f4 = tid + it * 256;
            const int r = f4 >> 5;
            const int c4 = (f4 & 31) * 4;
            *(float4*)&KVs[r][c4] = *(const float4*)(V + (size_t)(s0 + r) * DD + h * HDIM + c4);
        }
        __syncthreads();

#pragma unroll
        for (int i = 0; i < 4; ++i)
#pragma unroll
            for (int c = 0; c < 8; ++c) O[i][c] *= alpha_r[i];

#pragma unroll 4
        for (int s = 0; s < BS; ++s) {
            const float4 v0 = *(float4*)&KVs[s][tx * 8];
            const float4 v1 = *(float4*)&KVs[s][tx * 8 + 4];
#pragma unroll
            for (int i = 0; i < 4; ++i) {
                const float p = Ps[ty * 4 + i][s];
                O[i][0] = fmaf(p, v0.x, O[i][0]);
                O[i][1] = fmaf(p, v0.y, O[i][1]);
                O[i][2] = fmaf(p, v0.z, O[i][2]);
                O[i][3] = fmaf(p, v0.w, O[i][3]);
                O[i][4] = fmaf(p, v1.x, O[i][4]);
                O[i][5] = fmaf(p, v1.y, O[i][5]);
                O[i][6] = fmaf(p, v1.z, O[i][6]);
                O[i][7] = fmaf(p, v1.w, O[i][7]);
            }
        }
        __syncthreads();
    }

#pragma unroll
    for (int i = 0; i < 4; ++i) {
        const int r = ty * 4 + i;
        const float inv = 1.f / l_i[i];
        _Float16* dst = Aout + (size_t)(q0 + r) * DD + h * HDIM + tx * 8;
        half8 o;
#pragma unroll
        for (int c = 0; c < 8; ++c) o[c] = (_Float16)(O[i][c] * inv);
        *(half8*)dst = o;
    }
}

// ---------------------------------------------------------------------------
// Launch. ws layout: Q,K,V fp32 (3x16MB) + xh f16 (8MB, reused as attention
// output Abh after qkv_gemm consumes it) + Wqt..Wot f16 (4x8MB) = 88 MB.
// ---------------------------------------------------------------------------
extern "C" void kernel_launch(void* const* d_in, const int* in_sizes, int n_in,
                              void* d_out, int out_size, void* d_ws, size_t ws_size,
                              hipStream_t stream) {
    const float* x  = (const float*)d_in[0];
    const float* Wq = (const float*)d_in[1];
    const float* Wk = (const float*)d_in[2];
    const float* Wv = (const float*)d_in[3];
    const float* Wo = (const float*)d_in[4];
    const float* sn = (const float*)d_in[5];
    const float* cs = (const float*)d_in[6];
    const int* doc  = (const int*)d_in[7];
    float* out = (float*)d_out;

    const size_t NE = (size_t)TT * DD;  // 4M elements
    float* Q  = (float*)d_ws;
    float* Kb = Q  + NE;
    float* Vb = Kb + NE;
    _Float16* xh  = (_Float16*)(Vb + NE);
    _Float16* Wqt = xh  + NE;
    _Float16* Wkt = Wqt + NE;
    _Float16* Wvt = Wkt + NE;
    _Float16* Wot = Wvt + NE;
    _Float16* Abh = xh;   // reuse: xh consumed by qkv_gemm before attn writes

    const dim3 bb(256);

    conv_f16_kernel<<<dim3(NE / (256 * 4)), bb, 0, stream>>>(x, xh);
    tconv_kernel<<<dim3(DD / 32, DD / 32, 4), bb, 0, stream>>>(Wq, Wk, Wv, Wo, Wqt, Wkt, Wvt, Wot);
    qkv_gemm_kernel<<<dim3(DD / 128, TT / 128, 3), bb, 0, stream>>>(xh, Wqt, Wkt, Wvt, Q, Kb, Vb);
    rope_kernel<<<dim3((TT * NH * 64) / 256), bb, 0, stream>>>(Q, Kb, sn, cs);
    attn_kernel<<<dim3(TT / 64, NH), bb, 0, stream>>>(Q, Kb, Vb, doc, Abh);
    ogemm_kernel<<<dim3(DD / 128, TT / 128), bb, 0, stream>>>(Abh, Wot, out);
}

// Round 5
// 270.162 us; speedup vs baseline: 4.4603x; 1.5126x over previous
//
#include <hip/hip_runtime.h>

// Problem constants: B=1, T=2048, D=2048, H=16, HD=128
#define TT 2048
#define DD 2048
#define NH 16
#define HDIM 128

typedef _Float16 half8 __attribute__((ext_vector_type(8)));
typedef _Float16 half4 __attribute__((ext_vector_type(4)));
typedef float floatx4 __attribute__((ext_vector_type(4)));

// ---------------------------------------------------------------------------
// fp32 -> f16 elementwise convert
// ---------------------------------------------------------------------------
__global__ __launch_bounds__(256) void conv_f16_kernel(const float* __restrict__ in,
                                                       _Float16* __restrict__ out) {
    const int i = (blockIdx.x * 256 + threadIdx.x) * 4;
    const float4 v = *(const float4*)(in + i);
    half4 o;
    o[0] = (_Float16)v.x; o[1] = (_Float16)v.y;
    o[2] = (_Float16)v.z; o[3] = (_Float16)v.w;
    *(half4*)(out + i) = o;
}

// ---------------------------------------------------------------------------
// fp32 W[K][N] -> f16 Wt[N][K] transpose+convert, 32x32 LDS tile.
// ---------------------------------------------------------------------------
__global__ __launch_bounds__(256) void tconv_kernel(const float* __restrict__ W0,
                                                    const float* __restrict__ W1,
                                                    const float* __restrict__ W2,
                                                    const float* __restrict__ W3,
                                                    _Float16* __restrict__ O0,
                                                    _Float16* __restrict__ O1,
                                                    _Float16* __restrict__ O2,
                                                    _Float16* __restrict__ O3) {
    const float* W = blockIdx.z == 0 ? W0 : (blockIdx.z == 1 ? W1 : (blockIdx.z == 2 ? W2 : W3));
    _Float16* O = blockIdx.z == 0 ? O0 : (blockIdx.z == 1 ? O1 : (blockIdx.z == 2 ? O2 : O3));
    __shared__ float T[32][33];
    const int tx = threadIdx.x & 7;
    const int ty = threadIdx.x >> 3;
    const int k0 = blockIdx.y * 32;
    const int n0 = blockIdx.x * 32;
    const float4 v = *(const float4*)(W + (size_t)(k0 + ty) * DD + n0 + tx * 4);
    T[ty][tx * 4 + 0] = v.x;
    T[ty][tx * 4 + 1] = v.y;
    T[ty][tx * 4 + 2] = v.z;
    T[ty][tx * 4 + 3] = v.w;
    __syncthreads();
    half4 o;
    o[0] = (_Float16)T[tx * 4 + 0][ty];
    o[1] = (_Float16)T[tx * 4 + 1][ty];
    o[2] = (_Float16)T[tx * 4 + 2][ty];
    o[3] = (_Float16)T[tx * 4 + 3][ty];
    *(half4*)(O + (size_t)(n0 + ty) * DD + k0 + tx * 4) = o;
}

// ---------------------------------------------------------------------------
// MFMA f16 GEMM body (verified R3). MODE: 0 = fp32 C[row][col],
// 1 = f16 C[row][col], 2 = f16 transposed C[col][row].
// ---------------------------------------------------------------------------
template <int MODE>
__device__ __forceinline__ void hgemm_body(const _Float16* __restrict__ A,
                                           const _Float16* __restrict__ Bt,
                                           float* __restrict__ Cf,
                                           _Float16* __restrict__ Ch,
                                           const int row0, const int col0) {
    __shared__ __align__(16) _Float16 Al[128 * 32];
    __shared__ __align__(16) _Float16 Bl[128 * 32];

    const int tid = threadIdx.x;
    const int lane = tid & 63;
    const int w = tid >> 6;
    const int quad = lane >> 4;
    const int lr = lane & 15;
    const int wr = (w >> 1) * 64;
    const int wc = (w & 1) * 64;

    floatx4 acc[4][4];
#pragma unroll
    for (int i = 0; i < 4; ++i)
#pragma unroll
        for (int j = 0; j < 4; ++j)
            acc[i][j] = (floatx4){0.f, 0.f, 0.f, 0.f};

    const int subrow = lane >> 2;
    const int lblk = lane & 3;

    for (int k0 = 0; k0 < DD; k0 += 32) {
#pragma unroll
        for (int i = 0; i < 2; ++i) {
            const int ch = w * 2 + i;
            const int r = ch * 16 + subrow;
            const int gb = (lblk + (r >> 1)) & 3;
            const _Float16* ga = A + (size_t)(row0 + r) * DD + k0 + gb * 8;
            __builtin_amdgcn_global_load_lds(
                (const __attribute__((address_space(1))) void*)ga,
                (__attribute__((address_space(3))) void*)(Al + ch * 512), 16, 0, 0);
            const _Float16* gbp = Bt + (size_t)(col0 + r) * DD + k0 + gb * 8;
            __builtin_amdgcn_global_load_lds(
                (const __attribute__((address_space(1))) void*)gbp,
                (__attribute__((address_space(3))) void*)(Bl + ch * 512), 16, 0, 0);
        }
        __syncthreads();

        half8 af[4], bf[4];
#pragma unroll
        for (int i = 0; i < 4; ++i) {
            const int r = wr + i * 16 + lr;
            const int lb = (quad - (r >> 1)) & 3;
            af[i] = *(const half8*)&Al[r * 32 + lb * 8];
        }
#pragma unroll
        for (int j = 0; j < 4; ++j) {
            const int r = wc + j * 16 + lr;
            const int lb = (quad - (r >> 1)) & 3;
            bf[j] = *(const half8*)&Bl[r * 32 + lb * 8];
        }
#pragma unroll
        for (int i = 0; i < 4; ++i)
#pragma unroll
            for (int j = 0; j < 4; ++j)
                acc[i][j] = __builtin_amdgcn_mfma_f32_16x16x32_f16(af[i], bf[j], acc[i][j], 0, 0, 0);
        __syncthreads();
    }

    // epilogue: C/D layout col = lane&15, row = quad*4 + reg
#pragma unroll
    for (int i = 0; i < 4; ++i)
#pragma unroll
        for (int j = 0; j < 4; ++j) {
            const int col = col0 + wc + j * 16 + lr;
#pragma unroll
            for (int r = 0; r < 4; ++r) {
                const int row = row0 + wr + i * 16 + quad * 4 + r;
                if (MODE == 0) Cf[(size_t)row * DD + col] = acc[i][j][r];
                if (MODE == 1) Ch[(size_t)row * DD + col] = (_Float16)acc[i][j][r];
                if (MODE == 2) Ch[(size_t)col * DD + row] = (_Float16)acc[i][j][r];
            }
        }
}

// QKV fused: z=0 -> Qh (f16), z=1 -> Kh (f16), z=2 -> Vt (f16, transposed)
__global__ __launch_bounds__(256) void qkv_gemm_kernel(const _Float16* __restrict__ xh,
                                                       const _Float16* __restrict__ Wqt,
                                                       const _Float16* __restrict__ Wkt,
                                                       const _Float16* __restrict__ Wvt,
                                                       _Float16* __restrict__ Qh,
                                                       _Float16* __restrict__ Kh,
                                                       _Float16* __restrict__ Vt) {
    const int row0 = blockIdx.y * 128, col0 = blockIdx.x * 128;
    if (blockIdx.z == 0)      hgemm_body<1>(xh, Wqt, nullptr, Qh, row0, col0);
    else if (blockIdx.z == 1) hgemm_body<1>(xh, Wkt, nullptr, Kh, row0, col0);
    else                      hgemm_body<2>(xh, Wvt, nullptr, Vt, row0, col0);
}

__global__ __launch_bounds__(256) void ogemm_kernel(const _Float16* __restrict__ Ah,
                                                    const _Float16* __restrict__ Wot,
                                                    float* __restrict__ C) {
    hgemm_body<0>(Ah, Wot, C, nullptr, blockIdx.y * 128, blockIdx.x * 128);
}

// ---------------------------------------------------------------------------
// RoPE in-place on f16 Q and K (fp32 math, one extra f16 rounding).
// ---------------------------------------------------------------------------
__global__ __launch_bounds__(256) void rope_f16_kernel(_Float16* __restrict__ Qh,
                                                       _Float16* __restrict__ Kh,
                                                       const float* __restrict__ sn,
                                                       const float* __restrict__ cs) {
    const int idx = blockIdx.x * 256 + threadIdx.x;  // T*16*16 threads
    const int i = (idx & 15) * 4;
    const int h = (idx >> 4) & 15;
    const int t = idx >> 8;
    const size_t base = (size_t)t * DD + h * HDIM + i;
    half4 qa = *(half4*)(Qh + base), qb = *(half4*)(Qh + base + 64);
    half4 ka = *(half4*)(Kh + base), kb = *(half4*)(Kh + base + 64);
    half4 qa2, qb2, ka2, kb2;
#pragma unroll
    for (int j = 0; j < 4; ++j) {
        const float s1 = sn[t * HDIM + i + j];
        const float c1 = cs[t * HDIM + i + j];
        const float s2 = sn[t * HDIM + i + 64 + j];
        const float c2 = cs[t * HDIM + i + 64 + j];
        qa2[j] = (_Float16)((float)qa[j] * c1 - (float)qb[j] * s1);
        qb2[j] = (_Float16)((float)qb[j] * c2 + (float)qa[j] * s2);
        ka2[j] = (_Float16)((float)ka[j] * c1 - (float)kb[j] * s1);
        kb2[j] = (_Float16)((float)kb[j] * c2 + (float)ka[j] * s2);
    }
    *(half4*)(Qh + base) = qa2;
    *(half4*)(Qh + base + 64) = qb2;
    *(half4*)(Kh + base) = ka2;
    *(half4*)(Kh + base + 64) = kb2;
}

// ---------------------------------------------------------------------------
// MFMA flash attention. Block = 4 waves, BQ=64 (16 q-rows/wave), BS=32.
// Q frags in registers; K staged swizzled via global_load_lds; V staged from
// the pre-transposed Vt[d][t] global layout. P round-trips per-wave LDS
// (C-layout -> A-layout). Doc mask via -1e30 annihilation.
// ---------------------------------------------------------------------------
__global__ __launch_bounds__(256) void attn_kernel(const _Float16* __restrict__ Qh,
                                                   const _Float16* __restrict__ Kh,
                                                   const _Float16* __restrict__ Vt,
                                                   const int* __restrict__ doc_ids,
                                                   _Float16* __restrict__ Aout) {
    __shared__ __align__(16) _Float16 KV[32 * 128 + 128 * 32];  // Kl | Vl (16KB)
    __shared__ __align__(16) _Float16 Ps[4][16 * 40];           // per-wave P
    __shared__ int sdoc[32];
    _Float16* Kl = KV;
    _Float16* Vl = KV + 32 * 128;

    const int tid = threadIdx.x;
    const int lane = tid & 63;
    const int w = tid >> 6;
    const int quad = lane >> 4;
    const int lr = lane & 15;
    const int h = blockIdx.y;
    const int q0 = blockIdx.x * 64;

    // Q fragments (A-layout): row = q0 + w*16 + lr, k = c*32 + quad*8 + j
    const int qrow = q0 + w * 16 + lr;
    half8 qf[4];
#pragma unroll
    for (int c = 0; c < 4; ++c)
        qf[c] = *(const half8*)(Qh + (size_t)qrow * DD + h * HDIM + c * 32 + quad * 8);

    // docs of this lane's C-layout rows (quad*4 + r)
    int qd[4];
#pragma unroll
    for (int r = 0; r < 4; ++r)
        qd[r] = doc_ids[q0 + w * 16 + quad * 4 + r];

    float m_r[4], l_r[4];
    floatx4 Oacc[8];
#pragma unroll
    for (int r = 0; r < 4; ++r) { m_r[r] = -1e30f; l_r[r] = 0.f; }
#pragma unroll
    for (int n = 0; n < 8; ++n) Oacc[n] = (floatx4){0.f, 0.f, 0.f, 0.f};

    // binary search: first index with doc == doc_ids[q0]
    const int d0 = doc_ids[q0];
    int lo = 0, hi = q0;
    while (lo < hi) {
        const int mid = (lo + hi) >> 1;
        if (doc_ids[mid] < d0) lo = mid + 1; else hi = mid;
    }
    const int s_begin = lo & ~31;

    for (int s0 = s_begin; s0 < q0 + 64; s0 += 32) {
        // ---- stage K (chunk-swizzled) + Vt ----
#pragma unroll
        for (int i = 0; i < 2; ++i) {
            const int ch = w * 2 + i;
            {   // K: 4 rows x 256B per instr; LDS[r][p] holds global chunk (p - r)&15
                const int r = ch * 4 + (lane >> 4);
                const int g = ((lane & 15) - r) & 15;
                const _Float16* src = Kh + (size_t)(s0 + r) * DD + h * HDIM + g * 8;
                __builtin_amdgcn_global_load_lds(
                    (const __attribute__((address_space(1))) void*)src,
                    (__attribute__((address_space(3))) void*)(Kl + ch * 512), 16, 0, 0);
            }
            {   // Vt: 16 rows x 64B per instr, natural [d][s] layout
                const int dl = ch * 16 + (lane >> 2);
                const _Float16* src = Vt + (size_t)(h * HDIM + dl) * TT + s0 + (lane & 3) * 8;
                __builtin_amdgcn_global_load_lds(
                    (const __attribute__((address_space(1))) void*)src,
                    (__attribute__((address_space(3))) void*)(Vl + ch * 512), 16, 0, 0);
            }
        }
        if (tid < 32) sdoc[tid] = doc_ids[s0 + tid];
        __syncthreads();

        // ---- S = Q K^T : two 16x16 col-blocks ----
        floatx4 S0 = (floatx4){0.f, 0.f, 0.f, 0.f};
        floatx4 S1 = (floatx4){0.f, 0.f, 0.f, 0.f};
#pragma unroll
        for (int c = 0; c < 4; ++c) {
            const int p = (c * 4 + quad + lr) & 15;
            half8 b0 = *(const half8*)&Kl[(lr) * 128 + p * 8];
            half8 b1 = *(const half8*)&Kl[(16 + lr) * 128 + p * 8];
            S0 = __builtin_amdgcn_mfma_f32_16x16x32_f16(qf[c], b0, S0, 0, 0, 0);
            S1 = __builtin_amdgcn_mfma_f32_16x16x32_f16(qf[c], b1, S1, 0, 0, 0);
        }

        // ---- mask + online softmax (C layout: col=lr, row=quad*4+r) ----
        const float scale = 0.08838834764831845f;
        float alpha[4];
#pragma unroll
        for (int r = 0; r < 4; ++r) {
            const int qg = q0 + w * 16 + quad * 4 + r;
            const bool v0 = (s0 + lr <= qg) && (sdoc[lr] == qd[r]);
            const bool v1 = (s0 + 16 + lr <= qg) && (sdoc[16 + lr] == qd[r]);
            const float x0 = v0 ? S0[r] * scale : -1e30f;
            const float x1 = v1 ? S1[r] * scale : -1e30f;
            float m = fmaxf(x0, x1);
            m = fmaxf(m, __shfl_xor(m, 1));
            m = fmaxf(m, __shfl_xor(m, 2));
            m = fmaxf(m, __shfl_xor(m, 4));
            m = fmaxf(m, __shfl_xor(m, 8));
            const float mn = fmaxf(m_r[r], m);
            const float e0 = __expf(x0 - mn);
            const float e1 = __expf(x1 - mn);
            float ts = e0 + e1;
            ts += __shfl_xor(ts, 1);
            ts += __shfl_xor(ts, 2);
            ts += __shfl_xor(ts, 4);
            ts += __shfl_xor(ts, 8);
            alpha[r] = __expf(m_r[r] - mn);
            l_r[r] = l_r[r] * alpha[r] + ts;
            m_r[r] = mn;
            Ps[w][(quad * 4 + r) * 40 + lr] = (_Float16)e0;
            Ps[w][(quad * 4 + r) * 40 + 16 + lr] = (_Float16)e1;
        }

        // ---- O = O*alpha + P V  (A-frag from per-wave Ps, B-frag from Vl) ----
#pragma unroll
        for (int n = 0; n < 8; ++n)
#pragma unroll
            for (int r = 0; r < 4; ++r) Oacc[n][r] *= alpha[r];

        const half8 af = *(const half8*)&Ps[w][lr * 40 + quad * 8];
#pragma unroll
        for (int n = 0; n < 8; ++n) {
            const half8 bv = *(const half8*)&Vl[(n * 16 + lr) * 32 + quad * 8];
            Oacc[n] = __builtin_amdgcn_mfma_f32_16x16x32_f16(af, bv, Oacc[n], 0, 0, 0);
        }
        __syncthreads();
    }

    // ---- normalize, LDS round-trip for coalesced f16 store ----
    float inv[4];
#pragma unroll
    for (int r = 0; r < 4; ++r) inv[r] = 1.f / l_r[r];
    _Float16* Ol = KV;  // reuse (all K/V reads fenced by loop-end barrier)
#pragma unroll
    for (int n = 0; n < 8; ++n)
#pragma unroll
        for (int r = 0; r < 4; ++r)
            Ol[(w * 16 + quad * 4 + r) * 128 + n * 16 + lr] = (_Float16)(Oacc[n][r] * inv[r]);
    __syncthreads();
#pragma unroll
    for (int it = 0; it < 4; ++it) {
        const int idx = tid + it * 256;
        const int row = idx >> 4, c8 = idx & 15;   // FIXED: 64 rows x 16 half8 groups
        *(half8*)(Aout + (size_t)(q0 + row) * DD + h * HDIM + c8 * 8) =
            *(const half8*)&Ol[row * 128 + c8 * 8];
    }
}

// ---------------------------------------------------------------------------
// Launch. ws (all f16, 4M elems = 8MB each): xh, Wqt, Wkt, Wvt, Wot, Qh, Kh,
// Vt = 64 MB. Attention output reuses xh (dead after qkv_gemm).
// ---------------------------------------------------------------------------
extern "C" void kernel_launch(void* const* d_in, const int* in_sizes, int n_in,
                              void* d_out, int out_size, void* d_ws, size_t ws_size,
                              hipStream_t stream) {
    const float* x  = (const float*)d_in[0];
    const float* Wq = (const float*)d_in[1];
    const float* Wk = (const float*)d_in[2];
    const float* Wv = (const float*)d_in[3];
    const float* Wo = (const float*)d_in[4];
    const float* sn = (const float*)d_in[5];
    const float* cs = (const float*)d_in[6];
    const int* doc  = (const int*)d_in[7];
    float* out = (float*)d_out;

    const size_t NE = (size_t)TT * DD;
    _Float16* xh  = (_Float16*)d_ws;
    _Float16* Wqt = xh  + NE;
    _Float16* Wkt = Wqt + NE;
    _Float16* Wvt = Wkt + NE;
    _Float16* Wot = Wvt + NE;
    _Float16* Qh  = Wot + NE;
    _Float16* Kh  = Qh  + NE;
    _Float16* Vt  = Kh  + NE;
    _Float16* Abh = xh;  // reuse: xh consumed by qkv_gemm before attn writes

    const dim3 bb(256);

    conv_f16_kernel<<<dim3(NE / (256 * 4)), bb, 0, stream>>>(x, xh);
    tconv_kernel<<<dim3(DD / 32, DD / 32, 4), bb, 0, stream>>>(Wq, Wk, Wv, Wo, Wqt, Wkt, Wvt, Wot);
    qkv_gemm_kernel<<<dim3(DD / 128, TT / 128, 3), bb, 0, stream>>>(xh, Wqt, Wkt, Wvt, Qh, Kh, Vt);
    rope_f16_kernel<<<dim3((TT * NH * 16) / 256), bb, 0, stream>>>(Qh, Kh, sn, cs);
    attn_kernel<<<dim3(TT / 64, NH), bb, 0, stream>>>(Qh, Kh, Vt, doc, Abh);
    ogemm_kernel<<<dim3(DD / 128, TT / 128), bb, 0, stream>>>(Abh, Wot, out);
}